// Round 7
// baseline (172.670 us; speedup 1.0000x reference)
//
#include <hip/hip_runtime.h>

// RBF causal attention: out[m] = sum_{j<=m} exp(-0.125*||q_m - k_j||^2) * v_j
// B=2 H=16 S=2048 D=64, fp32 in/out.
// fp16 hi/lo-split QK (3 MFMAs ~ fp32 accuracy), fp16 PV with p scaled 2^14.
// R7: (a) double-buffered global_load_lds with ONE barrier per iteration --
// DMA(i+1) issued before compute(i), so the barrier's vmcnt drain lands after
// compute and the DMA fully hides; (b) P C-layout -> A-layout via a single
// shfl_xor(32) register exchange: kills the 16KB sP LDS round-trip and its
// 5M bank-conflict cycles, frees LDS for the 2nd buffer.
// LDS 2x25.6KB = 51.2KB -> 3 blocks/CU; grid 768 = exactly 3/CU.

constexpr int S_LEN = 2048;
constexpr int HD    = 64;
constexpr int BM    = 128;   // Q rows per block (4 waves x 32 rows)
constexpr int BN    = 64;    // K/V rows per tile
constexpr float SCALE = 0.125f;
constexpr float LOG2E = 1.44269504088896f;
constexpr float C2    = 2.f * SCALE * LOG2E;   // coeff on qk term
constexpr int TS = 25600;    // ws bytes per (bh,jt) tile: Khi 8K|Klo 8K|Vt 8K|ksq 256|pad

typedef _Float16 half8  __attribute__((ext_vector_type(8)));
typedef _Float16 half4  __attribute__((ext_vector_type(4)));
typedef float    f32x4  __attribute__((ext_vector_type(4)));
typedef float    f32x16 __attribute__((ext_vector_type(16)));
typedef unsigned int u32;

union U2H4 { u32 u[2]; half4 h; };
union U4H8 { u32 u[4]; half8 h; };

// 16B-chunk XOR swizzle (rows of 64 halves = 8 chunks of 8 halves).
__device__ __forceinline__ int swz(int row, int chunk) {
  return (row << 3) + (chunk ^ (row & 7));
}

// ---------------- pass 1: preconvert K/V into LDS-image tiles in ws ----------
__global__ __launch_bounds__(256, 4)
void preconvert(const float* __restrict__ Kp, const float* __restrict__ Vp,
                char* __restrict__ ws) {
  const int x  = blockIdx.x;
  const int bh = x >> 5, jt = x & 31;
  const int t  = threadIdx.x;
  const int w  = t >> 6, lane = t & 63;

  char* img = ws + (size_t)(bh * 32 + jt) * TS;
  half8* imgKh = (half8*)img;
  half8* imgKl = imgKh + 512;
  half8* imgVt = imgKh + 1024;
  float* ksqp  = (float*)(img + 24576);

  const float* Kt = Kp + ((size_t)bh * S_LEN + jt * BN) * HD;
  const float* Vt = Vp + ((size_t)bh * S_LEN + jt * BN) * HD;

  #pragma unroll
  for (int i = 0; i < 4; ++i) {
    const int id  = t + 256 * i;
    const int row = id >> 4;
    const int d4  = id & 15;
    const f32x4 f = *(const f32x4*)(Kt + row * HD + d4 * 4);
    half4 hv, lv;
    float ss = 0.f;
    #pragma unroll
    for (int c = 0; c < 4; ++c) {
      const float fv = f[c];
      const _Float16 hi = (_Float16)fv;
      hv[c] = hi;
      lv[c] = (_Float16)(fv - (float)hi);
      ss += fv * fv;
    }
    ((half4*)&imgKh[swz(row, d4 >> 1)])[d4 & 1] = hv;
    ((half4*)&imgKl[swz(row, d4 >> 1)])[d4 & 1] = lv;
    #pragma unroll
    for (int m = 1; m < 16; m <<= 1) ss += __shfl_xor(ss, m);
    if ((t & 15) == 0) ksqp[row] = ss * (SCALE * LOG2E) - 14.0f;  // bias folded
  }
  // V transpose: lane holds col d=lane, rows w*16..w*16+15
  float vr[16];
  #pragma unroll
  for (int i = 0; i < 16; ++i) vr[i] = Vt[(w * 16 + i) * HD + lane];
  half8 v0, v1;
  #pragma unroll
  for (int i = 0; i < 8; ++i) { v0[i] = (_Float16)vr[i]; v1[i] = (_Float16)vr[8 + i]; }
  imgVt[swz(lane, 2 * w + 0)] = v0;
  imgVt[swz(lane, 2 * w + 1)] = v1;
}

// ---------------- main kernel ------------------------------------------------
__global__ __launch_bounds__(256, 3)
void rbf_causal_attn(const float* __restrict__ Qp, const char* __restrict__ ws,
                     float* __restrict__ Op) {
  __shared__ __align__(16) char sBuf[2][TS];   // double-buffered tile image

  const int x    = blockIdx.x;                 // 0..767
  const int xcd  = x & 7;
  const int idx  = x >> 3;                     // 0..95
  const int bh   = xcd * 4 + (idx & 3);        // 4 bh per XCD (L2 reuse of ws)
  const int a    = idx >> 2;                   // arc 0..23
  const int t    = threadIdx.x;
  const int w    = t >> 6;
  const int lane = t & 63;
  const int l31  = lane & 31;
  const int l5   = lane >> 5;                  // 0/1

  // arc: first 8 arcs take 12 j-iters, rest 11 (total 272 per bh)
  const int start = (a < 8) ? 12 * a : 96 + 11 * (a - 8);
  const int len   = (a < 8) ? 12 : 11;

  // flattened (qt descending from 15, jt ascending 0..2qt+1) -> (qt, jt)
  int rem = start, qt = 15;
  while (rem >= 2 * qt + 2) { rem -= 2 * qt + 2; --qt; }
  int jt = rem;

  const char* wsb = ws + (size_t)bh * 32 * TS;

  half8 qh[4], ql[4];   // B-operand Q frags: row w*32+l31, k-chunk ks*16+l5*8
  float qsq;            // SCALE*LOG2E*|q_row|^2
  f32x16 oacc[2];       // O accumulator (x 2^14), dtile 0/1
  #pragma unroll
  for (int d = 0; d < 2; ++d)
    #pragma unroll
    for (int e = 0; e < 16; ++e) oacc[d][e] = 0.f;

  auto load_q = [&](int qtile) {
    const float* Qg = Qp + ((size_t)bh * S_LEN + (size_t)qtile * BM + w * 32 + l31) * HD;
    float ss = 0.f;
    #pragma unroll
    for (int ks = 0; ks < 4; ++ks) {
      const int d0 = ks * 16 + l5 * 8;
      const f32x4 fa = *(const f32x4*)(Qg + d0);
      const f32x4 fb = *(const f32x4*)(Qg + d0 + 4);
      half8 h, l;
      #pragma unroll
      for (int c = 0; c < 4; ++c) {
        const float va = fa[c], vb = fb[c];
        const _Float16 ha = (_Float16)va, hb = (_Float16)vb;
        h[c] = ha;  h[c + 4] = hb;
        l[c] = (_Float16)(va - (float)ha);
        l[c + 4] = (_Float16)(vb - (float)hb);
        ss += va * va + vb * vb;
      }
      qh[ks] = h;  ql[ks] = l;
    }
    ss += __shfl_xor(ss, 32);   // combine l5 halves -> full row sum
    qsq = ss * (SCALE * LOG2E);
  };

  // issue global->LDS DMA for tile jt into buffer dst (no wait here)
  auto dma = [&](int jtile, char* dst) {
    const char* gt = wsb + (size_t)jtile * TS;
    #pragma unroll
    for (int i = 0; i < 6; ++i) {
      const int off = w * 6144 + i * 1024;
      __builtin_amdgcn_global_load_lds((const unsigned int*)(gt + off + lane * 16),
                                       (unsigned int*)(dst + off), 16, 0, 0);
    }
    if (w == 0)
      __builtin_amdgcn_global_load_lds((const unsigned int*)(gt + 24576 + lane * 16),
                                       (unsigned int*)(dst + 24576), 16, 0, 0);
  };

  auto flush = [&](int qtile) {
    #pragma unroll
    for (int dt = 0; dt < 2; ++dt)
      #pragma unroll
      for (int r = 0; r < 16; ++r) {
        const int row = qtile * BM + w * 32 + (r & 3) + 8 * (r >> 2) + 4 * l5;
        atomicAdd(Op + ((size_t)bh * S_LEN + row) * HD + dt * 32 + l31,
                  oacc[dt][r] * 6.103515625e-05f);   // * 2^-14
      }
  };

  // ---- one tile: S^T = K*Q^T (hi/lo), exp2, shfl-exchange, O += P*V ----
  auto compute = [&](int qtile, int jtile, const char* sT) {
    const half8* sKh = (const half8*)sT;
    const half8* sKl = sKh + 512;
    const half8* sVt = sKh + 1024;
    const float* sksq = (const float*)(sT + 24576);

    const bool need_mask = (jtile >= 2 * qtile);
    const int mg = qtile * BM + w * 32 + l31;
    u32 pk[2][4][2];   // packed P: [ntile][gr][half4-as-2xu32]

    #pragma unroll
    for (int ntile = 0; ntile < 2; ++ntile) {
      f32x16 acc;
      #pragma unroll
      for (int e = 0; e < 16; ++e) acc[e] = 0.f;
      #pragma unroll
      for (int ks = 0; ks < 4; ++ks) {
        const int rr = ntile * 32 + l31;
        const int ch = (2 * ks + l5) ^ (rr & 7);
        const half8 kh = sKh[(rr << 3) + ch];
        const half8 kl = sKl[(rr << 3) + ch];
        acc = __builtin_amdgcn_mfma_f32_32x32x16_f16(kh, qh[ks], acc, 0, 0, 0);
        acc = __builtin_amdgcn_mfma_f32_32x32x16_f16(kh, ql[ks], acc, 0, 0, 0);
        acc = __builtin_amdgcn_mfma_f32_32x32x16_f16(kl, qh[ks], acc, 0, 0, 0);
      }
      #pragma unroll
      for (int g = 0; g < 4; ++g) {
        const f32x4 k4 = *(const f32x4*)(sksq + ntile * 32 + 8 * g + 4 * l5);
        half4 h4;
        #pragma unroll
        for (int rr = 0; rr < 4; ++rr) {
          // log2(2^14 p) = C2*qk - qsq' - (ksq' - 14)
          const float lg = __builtin_fmaf(C2, acc[g * 4 + rr], -k4[rr]) - qsq;
          float pv = __builtin_amdgcn_exp2f(lg);
          if (need_mask) {
            const int ng = jtile * BN + ntile * 32 + 8 * g + 4 * l5 + rr;
            if (ng > mg) pv = 0.f;
          }
          h4[rr] = (_Float16)pv;
        }
        U2H4 u; u.h = h4;
        pk[ntile][g][0] = u.u[0];
        pk[ntile][g][1] = u.u[1];
      }
    }

    // PV: A-frag for k-run ks*16+l5*8 from own regs + partner (lane^32)
    #pragma unroll
    for (int ks = 0; ks < 4; ++ks) {
      const int nt  = ks >> 1;
      const int grk = (2 * ks + l5) & 3;       // group this lane keeps
      const int grs = (2 * ks + 1 - l5) & 3;   // group the partner needs
      const u32 k0 = pk[nt][grk][0], k1 = pk[nt][grk][1];
      const u32 r0 = (u32)__shfl_xor((int)pk[nt][grs][0], 32);
      const u32 r1 = (u32)__shfl_xor((int)pk[nt][grs][1], 32);
      U4H8 au;
      au.u[0] = l5 ? r0 : k0;  au.u[1] = l5 ? r1 : k1;   // j 0..3 (holder l5'=0)
      au.u[2] = l5 ? k0 : r0;  au.u[3] = l5 ? k1 : r1;   // j 4..7 (holder l5'=1)
      const half8 pa = au.h;
      #pragma unroll
      for (int dt = 0; dt < 2; ++dt) {
        const int rr = dt * 32 + l31;
        const half8 vt = sVt[(rr << 3) + ((2 * ks + l5) ^ (rr & 7))];
        oacc[dt] = __builtin_amdgcn_mfma_f32_32x32x16_f16(pa, vt, oacc[dt], 0, 0, 0);
      }
    }
  };

  // ---- main loop: single barrier per iteration, DMA(i+1) hides behind compute(i)
  load_q(qt);
  dma(jt, sBuf[0]);
  __syncthreads();                 // tile 0 resident

  #pragma unroll 1
  for (int step = 0; step < len; ++step) {
    int nqt = qt, njt = jt + 1;               // next flattened tile
    if (njt > 2 * qt + 1) { nqt = qt - 1; njt = 0; }

    if (step + 1 < len) dma(njt, sBuf[(step + 1) & 1]);   // prefetch next
    compute(qt, jt, sBuf[step & 1]);
    __syncthreads();   // drains next DMA (hidden behind compute) + guards bufs

    if (nqt != qt) {                           // finished q-tile qt
      flush(qt);
      if (step + 1 < len) {
        #pragma unroll
        for (int d = 0; d < 2; ++d)
          #pragma unroll
          for (int e = 0; e < 16; ++e) oacc[d][e] = 0.f;
        load_q(nqt);
      }
    } else if (step + 1 == len) {
      flush(qt);                               // arc ended mid q-tile
    }
    qt = nqt; jt = njt;
  }
}

extern "C" void kernel_launch(void* const* d_in, const int* in_sizes, int n_in,
                              void* d_out, int out_size, void* d_ws, size_t ws_size,
                              hipStream_t stream) {
  const float* q = (const float*)d_in[0];
  const float* k = (const float*)d_in[1];
  const float* v = (const float*)d_in[2];
  float* o = (float*)d_out;
  hipMemsetAsync(d_out, 0, (size_t)out_size * sizeof(float), stream);
  preconvert<<<dim3(1024), dim3(256), 0, stream>>>(k, v, (char*)d_ws);
  rbf_causal_attn<<<dim3(768), dim3(256), 0, stream>>>(q, (const char*)d_ws, o);
}

// Round 8
// 154.785 us; speedup vs baseline: 1.1156x; 1.1156x over previous
//
#include <hip/hip_runtime.h>

// RBF causal attention: out[m] = sum_{j<=m} exp(-0.125*||q_m - k_j||^2) * v_j
// B=2 H=16 S=2048 D=64, fp32 in/out.
// fp16 hi/lo-split QK (3 MFMAs ~ fp32 accuracy), fp16 PV with p scaled 2^14.
// R8: R7 structure (pre-swizzled ws tiles, double-buffered global_load_lds,
// one barrier/iter, P C->A layout via shfl_xor(32) register exchange) but the
// exchange now uses COMPILE-TIME pk indices + cndmask selects. R7's runtime
// indices (grk=(2ks+l5)&3) forced scratch lowering: VALUBusy 28->55%, dur
// 69->90us. Never index a register array with a lane-dependent value.

constexpr int S_LEN = 2048;
constexpr int HD    = 64;
constexpr int BM    = 128;   // Q rows per block (4 waves x 32 rows)
constexpr int BN    = 64;    // K/V rows per tile
constexpr float SCALE = 0.125f;
constexpr float LOG2E = 1.44269504088896f;
constexpr float C2    = 2.f * SCALE * LOG2E;   // coeff on qk term
constexpr int TS = 25600;    // ws bytes per (bh,jt) tile: Khi 8K|Klo 8K|Vt 8K|ksq 256|pad

typedef _Float16 half8  __attribute__((ext_vector_type(8)));
typedef _Float16 half4  __attribute__((ext_vector_type(4)));
typedef float    f32x4  __attribute__((ext_vector_type(4)));
typedef float    f32x16 __attribute__((ext_vector_type(16)));
typedef unsigned int u32;

union U2H4 { u32 u[2]; half4 h; };
union U4H8 { u32 u[4]; half8 h; };

// 16B-chunk XOR swizzle (rows of 64 halves = 8 chunks of 8 halves).
__device__ __forceinline__ int swz(int row, int chunk) {
  return (row << 3) + (chunk ^ (row & 7));
}

// ---------------- pass 1: preconvert K/V into LDS-image tiles in ws ----------
__global__ __launch_bounds__(256, 4)
void preconvert(const float* __restrict__ Kp, const float* __restrict__ Vp,
                char* __restrict__ ws) {
  const int x  = blockIdx.x;
  const int bh = x >> 5, jt = x & 31;
  const int t  = threadIdx.x;
  const int w  = t >> 6, lane = t & 63;

  char* img = ws + (size_t)(bh * 32 + jt) * TS;
  half8* imgKh = (half8*)img;
  half8* imgKl = imgKh + 512;
  half8* imgVt = imgKh + 1024;
  float* ksqp  = (float*)(img + 24576);

  const float* Kt = Kp + ((size_t)bh * S_LEN + jt * BN) * HD;
  const float* Vt = Vp + ((size_t)bh * S_LEN + jt * BN) * HD;

  #pragma unroll
  for (int i = 0; i < 4; ++i) {
    const int id  = t + 256 * i;
    const int row = id >> 4;
    const int d4  = id & 15;
    const f32x4 f = *(const f32x4*)(Kt + row * HD + d4 * 4);
    half4 hv, lv;
    float ss = 0.f;
    #pragma unroll
    for (int c = 0; c < 4; ++c) {
      const float fv = f[c];
      const _Float16 hi = (_Float16)fv;
      hv[c] = hi;
      lv[c] = (_Float16)(fv - (float)hi);
      ss += fv * fv;
    }
    ((half4*)&imgKh[swz(row, d4 >> 1)])[d4 & 1] = hv;
    ((half4*)&imgKl[swz(row, d4 >> 1)])[d4 & 1] = lv;
    #pragma unroll
    for (int m = 1; m < 16; m <<= 1) ss += __shfl_xor(ss, m);
    if ((t & 15) == 0) ksqp[row] = ss * (SCALE * LOG2E) - 14.0f;  // bias folded
  }
  // V transpose: lane holds col d=lane, rows w*16..w*16+15
  float vr[16];
  #pragma unroll
  for (int i = 0; i < 16; ++i) vr[i] = Vt[(w * 16 + i) * HD + lane];
  half8 v0, v1;
  #pragma unroll
  for (int i = 0; i < 8; ++i) { v0[i] = (_Float16)vr[i]; v1[i] = (_Float16)vr[8 + i]; }
  imgVt[swz(lane, 2 * w + 0)] = v0;
  imgVt[swz(lane, 2 * w + 1)] = v1;
}

// ---------------- main kernel ------------------------------------------------
__global__ __launch_bounds__(256, 3)
void rbf_causal_attn(const float* __restrict__ Qp, const char* __restrict__ ws,
                     float* __restrict__ Op) {
  __shared__ __align__(16) char sBuf[2][TS];   // double-buffered tile image

  const int x    = blockIdx.x;                 // 0..767
  const int xcd  = x & 7;
  const int idx  = x >> 3;                     // 0..95
  const int bh   = xcd * 4 + (idx & 3);        // 4 bh per XCD (L2 reuse of ws)
  const int a    = idx >> 2;                   // arc 0..23
  const int t    = threadIdx.x;
  const int w    = t >> 6;
  const int lane = t & 63;
  const int l31  = lane & 31;
  const int l5   = lane >> 5;                  // 0/1
  const bool hi_half = (l5 != 0);

  // arc: first 8 arcs take 12 j-iters, rest 11 (total 272 per bh)
  const int start = (a < 8) ? 12 * a : 96 + 11 * (a - 8);
  const int len   = (a < 8) ? 12 : 11;

  // flattened (qt descending from 15, jt ascending 0..2qt+1) -> (qt, jt)
  int rem = start, qt = 15;
  while (rem >= 2 * qt + 2) { rem -= 2 * qt + 2; --qt; }
  int jt = rem;

  const char* wsb = ws + (size_t)bh * 32 * TS;

  half8 qh[4], ql[4];   // B-operand Q frags: row w*32+l31, k-chunk ks*16+l5*8
  float qsq;            // SCALE*LOG2E*|q_row|^2
  f32x16 oacc[2];       // O accumulator (x 2^14), dtile 0/1
  #pragma unroll
  for (int d = 0; d < 2; ++d)
    #pragma unroll
    for (int e = 0; e < 16; ++e) oacc[d][e] = 0.f;

  auto load_q = [&](int qtile) {
    const float* Qg = Qp + ((size_t)bh * S_LEN + (size_t)qtile * BM + w * 32 + l31) * HD;
    float ss = 0.f;
    #pragma unroll
    for (int ks = 0; ks < 4; ++ks) {
      const int d0 = ks * 16 + l5 * 8;
      const f32x4 fa = *(const f32x4*)(Qg + d0);
      const f32x4 fb = *(const f32x4*)(Qg + d0 + 4);
      half8 h, l;
      #pragma unroll
      for (int c = 0; c < 4; ++c) {
        const float va = fa[c], vb = fb[c];
        const _Float16 ha = (_Float16)va, hb = (_Float16)vb;
        h[c] = ha;  h[c + 4] = hb;
        l[c] = (_Float16)(va - (float)ha);
        l[c + 4] = (_Float16)(vb - (float)hb);
        ss += va * va + vb * vb;
      }
      qh[ks] = h;  ql[ks] = l;
    }
    ss += __shfl_xor(ss, 32);   // combine l5 halves -> full row sum
    qsq = ss * (SCALE * LOG2E);
  };

  // issue global->LDS DMA for tile jt into buffer dst (no wait here)
  auto dma = [&](int jtile, char* dst) {
    const char* gt = wsb + (size_t)jtile * TS;
    #pragma unroll
    for (int i = 0; i < 6; ++i) {
      const int off = w * 6144 + i * 1024;
      __builtin_amdgcn_global_load_lds((const unsigned int*)(gt + off + lane * 16),
                                       (unsigned int*)(dst + off), 16, 0, 0);
    }
    if (w == 0)
      __builtin_amdgcn_global_load_lds((const unsigned int*)(gt + 24576 + lane * 16),
                                       (unsigned int*)(dst + 24576), 16, 0, 0);
  };

  auto flush = [&](int qtile) {
    #pragma unroll
    for (int dt = 0; dt < 2; ++dt)
      #pragma unroll
      for (int r = 0; r < 16; ++r) {
        const int row = qtile * BM + w * 32 + (r & 3) + 8 * (r >> 2) + 4 * l5;
        atomicAdd(Op + ((size_t)bh * S_LEN + row) * HD + dt * 32 + l31,
                  oacc[dt][r] * 6.103515625e-05f);   // * 2^-14
      }
  };

  // ---- one tile: S^T = K*Q^T (hi/lo), exp2, shfl-exchange, O += P*V ----
  auto compute = [&](int qtile, int jtile, const char* sT) {
    const half8* sKh = (const half8*)sT;
    const half8* sKl = sKh + 512;
    const half8* sVt = sKh + 1024;
    const float* sksq = (const float*)(sT + 24576);

    const bool need_mask = (jtile >= 2 * qtile);
    const int mg = qtile * BM + w * 32 + l31;
    u32 pk[2][4][2];   // packed P: [ntile][group][half4-as-2xu32] (const idx only!)

    #pragma unroll
    for (int ntile = 0; ntile < 2; ++ntile) {
      f32x16 acc;
      #pragma unroll
      for (int e = 0; e < 16; ++e) acc[e] = 0.f;
      #pragma unroll
      for (int ks = 0; ks < 4; ++ks) {
        const int rr = ntile * 32 + l31;
        const int ch = (2 * ks + l5) ^ (rr & 7);
        const half8 kh = sKh[(rr << 3) + ch];
        const half8 kl = sKl[(rr << 3) + ch];
        acc = __builtin_amdgcn_mfma_f32_32x32x16_f16(kh, qh[ks], acc, 0, 0, 0);
        acc = __builtin_amdgcn_mfma_f32_32x32x16_f16(kh, ql[ks], acc, 0, 0, 0);
        acc = __builtin_amdgcn_mfma_f32_32x32x16_f16(kl, qh[ks], acc, 0, 0, 0);
      }
      #pragma unroll
      for (int g = 0; g < 4; ++g) {
        const f32x4 k4 = *(const f32x4*)(sksq + ntile * 32 + 8 * g + 4 * l5);
        half4 h4;
        #pragma unroll
        for (int rr = 0; rr < 4; ++rr) {
          // log2(2^14 p) = C2*qk - qsq' - (ksq' - 14)
          const float lg = __builtin_fmaf(C2, acc[g * 4 + rr], -k4[rr]) - qsq;
          float pv = __builtin_amdgcn_exp2f(lg);
          if (need_mask) {
            const int ng = jtile * BN + ntile * 32 + 8 * g + 4 * l5 + rr;
            if (ng > mg) pv = 0.f;
          }
          h4[rr] = (_Float16)pv;
        }
        U2H4 u; u.h = h4;
        pk[ntile][g][0] = u.u[0];
        pk[ntile][g][1] = u.u[1];
      }
    }

    // PV: A-frag for k-run 16ks+8*l5 built from own regs + partner (lane^32).
    // pa.lo = group Gs=(2ks+l5)&3 from the l5'=0 holder; pa.hi = same group
    // from the l5'=1 holder. All pk indices are COMPILE-TIME (Ge/Go).
    #pragma unroll
    for (int ks = 0; ks < 4; ++ks) {
      const int nt = ks >> 1;
      const int Ge = (2 * ks) & 3;       // group needed by l5=0 lanes
      const int Go = (2 * ks + 1) & 3;   // group needed by l5=1 lanes
      const u32 e0 = pk[nt][Ge][0], e1 = pk[nt][Ge][1];
      const u32 o0 = pk[nt][Go][0], o1 = pk[nt][Go][1];
      // I send what my partner needs: l5=0 sends Go, l5=1 sends Ge.
      const u32 s0 = hi_half ? e0 : o0;
      const u32 s1 = hi_half ? e1 : o1;
      const u32 r0 = (u32)__shfl_xor((int)s0, 32);
      const u32 r1 = (u32)__shfl_xor((int)s1, 32);
      U4H8 au;
      au.u[0] = hi_half ? r0 : e0;   // j0..3: from l5'=0 holder of my group
      au.u[1] = hi_half ? r1 : e1;
      au.u[2] = hi_half ? o0 : r0;   // j4..7: from l5'=1 holder of my group
      au.u[3] = hi_half ? o1 : r1;
      const half8 pa = au.h;
      #pragma unroll
      for (int dt = 0; dt < 2; ++dt) {
        const int rr = dt * 32 + l31;
        const half8 vt = sVt[(rr << 3) + ((2 * ks + l5) ^ (rr & 7))];
        oacc[dt] = __builtin_amdgcn_mfma_f32_32x32x16_f16(pa, vt, oacc[dt], 0, 0, 0);
      }
    }
  };

  // ---- main loop: single barrier per iteration, DMA(i+1) hides behind compute(i)
  load_q(qt);
  dma(jt, sBuf[0]);
  __syncthreads();                 // tile 0 resident

  #pragma unroll 1
  for (int step = 0; step < len; ++step) {
    int nqt = qt, njt = jt + 1;               // next flattened tile
    if (njt > 2 * qt + 1) { nqt = qt - 1; njt = 0; }

    if (step + 1 < len) dma(njt, sBuf[(step + 1) & 1]);   // prefetch next
    compute(qt, jt, sBuf[step & 1]);
    __syncthreads();   // drains next DMA (hidden behind compute) + guards bufs

    if (nqt != qt) {                           // finished q-tile qt
      flush(qt);
      if (step + 1 < len) {
        #pragma unroll
        for (int d = 0; d < 2; ++d)
          #pragma unroll
          for (int e = 0; e < 16; ++e) oacc[d][e] = 0.f;
        load_q(nqt);
      }
    } else if (step + 1 == len) {
      flush(qt);                               // arc ended mid q-tile
    }
    qt = nqt; jt = njt;
  }
}

extern "C" void kernel_launch(void* const* d_in, const int* in_sizes, int n_in,
                              void* d_out, int out_size, void* d_ws, size_t ws_size,
                              hipStream_t stream) {
  const float* q = (const float*)d_in[0];
  const float* k = (const float*)d_in[1];
  const float* v = (const float*)d_in[2];
  float* o = (float*)d_out;
  hipMemsetAsync(d_out, 0, (size_t)out_size * sizeof(float), stream);
  preconvert<<<dim3(1024), dim3(256), 0, stream>>>(k, v, (char*)d_ws);
  rbf_causal_attn<<<dim3(768), dim3(256), 0, stream>>>(q, (const char*)d_ws, o);
}